// Round 3
// baseline (1015.646 us; speedup 1.0000x reference)
//
#include <hip/hip_runtime.h>
#include <hip/hip_bf16.h>
#include <stdint.h>

// ---- fixed problem geometry (GRID_N=41, deterministic) ----
#define NV1 1681
#define NF1 3200
#define NS1 (3*NF1)      // 9600 edge slots
#define NV2 6561
#define NF2 12800
#define NS2 (3*NF2)      // 38400 edge slots
#define NV3 25921
#define D1  1286         // [verts(3) | perc1(1280) | verts(3)]
#define D2  2566         // [verts2(3) | perc2(1280) | s2(1283)]
#define DOUT 3843        // [perc3(1280) | s3(2563)]
#define TSIZE 131072
#define TMASK (TSIZE-1)

// ---------------- pooling ----------------
// one block per vertex; 256 threads loop over 1280 channels (5 iters,
// map boundaries 256/768 are multiples of 256 so each iter is map-uniform)
__global__ __launch_bounds__(256) void pool_kernel(
    const float* __restrict__ verts, int vstride, int nverts,
    const float* __restrict__ f3, const float* __restrict__ f4,
    const float* __restrict__ f5, float* __restrict__ out, int ostride)
{
  int v = blockIdx.x;
  if (v >= nverts) return;
  float X = verts[(size_t)v*vstride + 0];
  float Y = verts[(size_t)v*vstride + 1];
  float Z = verts[(size_t)v*vstride + 2];
  float p2 = Z + 0.8f;
  float px = (248.0f*X + 111.5f*Z + 89.2f) / p2;
  float py = (248.0f*Y + 111.5f*Z + 89.2f) / p2;

  const float* fptr[3] = {f3, f4, f5};
  const int dims[3] = {56, 28, 14};
  int o11[3], o12[3], o21[3], o22[3], dsq[3];
  float w11[3], w12[3], w21[3], w22[3];
#pragma unroll
  for (int m = 0; m < 3; ++m) {
    int dim = dims[m];
    float dimf = (float)dim;
    float x = fminf(fmaxf(px * dimf / 224.0f, 0.0f), dimf - 1.0f);
    float y = fminf(fmaxf(py * dimf / 224.0f, 0.0f), dimf - 1.0f);
    float x1 = floorf(x), x2 = ceilf(x);
    float y1 = floorf(y), y2 = ceilf(y);
    int xi1 = min(max((int)x1, 0), dim-1);
    int xi2 = min(max((int)x2, 0), dim-1);
    int yi1 = min(max((int)y1, 0), dim-1);
    int yi2 = min(max((int)y2, 0), dim-1);
    dsq[m] = dim*dim;
    o11[m] = xi1*dim + yi1;  o12[m] = xi1*dim + yi2;
    o21[m] = xi2*dim + yi1;  o22[m] = xi2*dim + yi2;
    w11[m] = (x2-x)*(y2-y);  w12[m] = (x2-x)*(y-y1);
    w21[m] = (x-x1)*(y2-y);  w22[m] = (x-x1)*(y-y1);
  }
#pragma unroll
  for (int k = 0; k < 5; ++k) {
    int c = k*256 + (int)threadIdx.x;
    int m  = (k == 0) ? 0 : (k < 3) ? 1 : 2;
    int cb = (m == 0) ? 0 : (m == 1) ? 256 : 768;
    const float* f = fptr[m];
    size_t base = (size_t)(c - cb) * dsq[m];
    float val = w11[m]*f[base+o11[m]] + w12[m]*f[base+o12[m]]
              + w21[m]*f[base+o21[m]] + w22[m]*f[base+o22[m]];
    out[(size_t)v*ostride + c] = val;
  }
}

// write verts into vf1 cols 0:3 and 1283:1286
__global__ void copyverts1(const float* __restrict__ verts, float* __restrict__ vf1)
{
  int i = blockIdx.x*blockDim.x + threadIdx.x;
  if (i >= NV1*3) return;
  int r = i/3, c = i - 3*r;
  float v = verts[i];
  vf1[(size_t)r*D1 + c] = v;
  vf1[(size_t)r*D1 + 1283 + c] = v;
}

// ---------------- connectivity (replicates np.unique first-occurrence ranks) ----
__global__ void edge_insert(const int* __restrict__ faces, int F, int V,
                            unsigned* __restrict__ tkey, int* __restrict__ tmin,
                            unsigned* __restrict__ keys)
{
  int s = blockIdx.x*blockDim.x + threadIdx.x;
  if (s >= 3*F) return;
  int f = s/3, k = s - 3*f;
  int a0 = faces[3*f + k];
  int a1 = faces[3*f + (k == 2 ? 0 : k+1)];
  int a = min(a0, a1), b = max(a0, a1);
  unsigned key = (unsigned)a * (unsigned)V + (unsigned)b;
  keys[s] = key;
  unsigned h = (key * 2654435761u) & TMASK;
  while (true) {
    unsigned old = atomicCAS(&tkey[h], 0xFFFFFFFFu, key);
    if (old == 0xFFFFFFFFu || old == key) { atomicMin(&tmin[h], s); break; }
    h = (h+1) & TMASK;
  }
}

__global__ void edge_first(const unsigned* __restrict__ keys, int S,
                           const unsigned* __restrict__ tkey, const int* __restrict__ tmin,
                           int* __restrict__ fslot)
{
  int s = blockIdx.x*blockDim.x + threadIdx.x;
  if (s >= S) return;
  unsigned key = keys[s];
  unsigned h = (key * 2654435761u) & TMASK;
  while (tkey[h] != key) h = (h+1) & TMASK;
  fslot[s] = tmin[h];
}

// exclusive prefix sum of (fslot[i]==i) over n elements, single block of 1024
__global__ __launch_bounds__(1024) void scan_excl(const int* __restrict__ fslot,
                                                  int* __restrict__ ranks, int n)
{
  __shared__ int tmp[1024];
  __shared__ int carry;
  if (threadIdx.x == 0) carry = 0;
  __syncthreads();
  for (int base = 0; base < n; base += 1024) {
    int i = base + (int)threadIdx.x;
    int v = (i < n && fslot[i] == i) ? 1 : 0;
    tmp[threadIdx.x] = v;
    __syncthreads();
    for (int off = 1; off < 1024; off <<= 1) {
      int t = (threadIdx.x >= (unsigned)off) ? tmp[threadIdx.x - off] : 0;
      __syncthreads();
      tmp[threadIdx.x] += t;
      __syncthreads();
    }
    if (i < n) ranks[i] = carry + tmp[threadIdx.x] - v;
    __syncthreads();
    if (threadIdx.x == 0) carry += tmp[1023];
    __syncthreads();
  }
}

__global__ void edge_mid(const unsigned* __restrict__ keys, const int* __restrict__ fslot,
                         const int* __restrict__ ranks, int S, int V,
                         int* __restrict__ mid, int* __restrict__ uea, int* __restrict__ ueb)
{
  int s = blockIdx.x*blockDim.x + threadIdx.x;
  if (s >= S) return;
  int fs = fslot[s];
  int r = ranks[fs];
  mid[s] = V + r;
  if (fs == s) {
    unsigned key = keys[s];
    uea[r] = (int)(key / (unsigned)V);
    ueb[r] = (int)(key % (unsigned)V);
  }
}

__global__ void new_faces(const int* __restrict__ faces, int F,
                          const int* __restrict__ mid, int* __restrict__ nf)
{
  int f = blockIdx.x*blockDim.x + threadIdx.x;
  if (f >= F) return;
  int i1 = faces[3*f], i2 = faces[3*f+1], i3 = faces[3*f+2];
  int i4 = mid[3*f], i5 = mid[3*f+1], i6 = mid[3*f+2];
  int* o = nf + 12*f;
  o[0]=i1; o[1]=i4; o[2]=i6;
  o[3]=i2; o[4]=i4; o[5]=i5;
  o[6]=i3; o[7]=i5; o[8]=i6;
  o[9]=i5; o[10]=i4; o[11]=i6;
}

// ---------------- subdivision feature propagation ----------------
// row r < Vold: copy; else midpoint of rows uea/ueb.  col<3 -> dstV, else dstS (pre-offset)
__global__ __launch_bounds__(256) void subdivide(
    const float* __restrict__ src, int D, int Vold,
    const int* __restrict__ uea, const int* __restrict__ ueb,
    float* __restrict__ dstV, int dvs, float* __restrict__ dstS, int dss)
{
  int c = blockIdx.x*blockDim.x + threadIdx.x;
  int r = blockIdx.y;
  if (c >= D) return;
  float val;
  if (r < Vold) {
    val = src[(size_t)r*D + c];
  } else {
    int e = r - Vold;
    int a = uea[e], b = ueb[e];
    val = 0.5f * (src[(size_t)a*D + c] + src[(size_t)b*D + c]);
  }
  if (c < 3) dstV[(size_t)r*dvs + c] = val;
  else       dstS[(size_t)r*dss + (c-3)] = val;
}

// ---------------- host ----------------
static inline char* bump(char*& p, size_t bytes) {
  char* r = p;
  p += (bytes + 255) & ~(size_t)255;
  return r;
}

extern "C" void kernel_launch(void* const* d_in, const int* in_sizes, int n_in,
                              void* d_out, int out_size, void* d_ws, size_t ws_size,
                              hipStream_t stream)
{
  const float* f3    = (const float*)d_in[0];
  const float* f4    = (const float*)d_in[1];
  const float* f5    = (const float*)d_in[2];
  const float* verts = (const float*)d_in[3];
  const int*   faces = (const int*)d_in[4];
  float* out = (float*)d_out;

  char* p = (char*)d_ws;
  float* vf1    = (float*)bump(p, (size_t)NV1*D1*4);
  float* vf2    = (float*)bump(p, (size_t)NV2*D2*4);
  float* verts3 = (float*)bump(p, (size_t)NV3*3*4);
  int*   faces2 = (int*)  bump(p, (size_t)NF2*3*4);
  unsigned* key1 = (unsigned*)bump(p, (size_t)NS1*4);
  int* fslot1 = (int*)bump(p, (size_t)NS1*4);
  int* rank1  = (int*)bump(p, (size_t)NS1*4);
  int* mid1   = (int*)bump(p, (size_t)NS1*4);
  int* ue1a   = (int*)bump(p, (size_t)NS1*4);
  int* ue1b   = (int*)bump(p, (size_t)NS1*4);
  unsigned* key2 = (unsigned*)bump(p, (size_t)NS2*4);
  int* fslot2 = (int*)bump(p, (size_t)NS2*4);
  int* rank2  = (int*)bump(p, (size_t)NS2*4);
  int* mid2   = (int*)bump(p, (size_t)NS2*4);
  int* ue2a   = (int*)bump(p, (size_t)NS2*4);
  int* ue2b   = (int*)bump(p, (size_t)NS2*4);
  unsigned* tkey1 = (unsigned*)bump(p, (size_t)TSIZE*4);
  int*      tmin1 = (int*)     bump(p, (size_t)TSIZE*4);
  unsigned* tkey2 = (unsigned*)bump(p, (size_t)TSIZE*4);
  int*      tmin2 = (int*)     bump(p, (size_t)TSIZE*4);

  // hash table init: keys = 0xFFFFFFFF (empty), mins = 0x7F7F7F7F (+inf)
  hipMemsetAsync(tkey1, 0xFF, (size_t)TSIZE*4, stream);
  hipMemsetAsync(tmin1, 0x7F, (size_t)TSIZE*4, stream);
  hipMemsetAsync(tkey2, 0xFF, (size_t)TSIZE*4, stream);
  hipMemsetAsync(tmin2, 0x7F, (size_t)TSIZE*4, stream);

  // ---- level 1 ----
  copyverts1<<<(NV1*3 + 255)/256, 256, 0, stream>>>(verts, vf1);
  pool_kernel<<<NV1, 256, 0, stream>>>(verts, 3, NV1, f3, f4, f5, vf1 + 3, D1);

  edge_insert<<<(NS1+255)/256, 256, 0, stream>>>(faces, NF1, NV1, tkey1, tmin1, key1);
  edge_first <<<(NS1+255)/256, 256, 0, stream>>>(key1, NS1, tkey1, tmin1, fslot1);
  scan_excl  <<<1, 1024, 0, stream>>>(fslot1, rank1, NS1);
  edge_mid   <<<(NS1+255)/256, 256, 0, stream>>>(key1, fslot1, rank1, NS1, NV1, mid1, ue1a, ue1b);
  new_faces  <<<(NF1+255)/256, 256, 0, stream>>>(faces, NF1, mid1, faces2);

  // vf2 = [verts2(0:3) | perc2(3:1283) | s2(1283:2566)]
  subdivide<<<dim3((D1+255)/256, NV2), 256, 0, stream>>>(
      vf1, D1, NV1, ue1a, ue1b, vf2, D2, vf2 + 1283, D2);
  pool_kernel<<<NV2, 256, 0, stream>>>(vf2, D2, NV2, f3, f4, f5, vf2 + 3, D2);

  // ---- level 2 ----
  edge_insert<<<(NS2+255)/256, 256, 0, stream>>>(faces2, NF2, NV2, tkey2, tmin2, key2);
  edge_first <<<(NS2+255)/256, 256, 0, stream>>>(key2, NS2, tkey2, tmin2, fslot2);
  scan_excl  <<<1, 1024, 0, stream>>>(fslot2, rank2, NS2);
  edge_mid   <<<(NS2+255)/256, 256, 0, stream>>>(key2, fslot2, rank2, NS2, NV2, mid2, ue2a, ue2b);

  // out = [perc3(0:1280) | s3(1280:3843)], verts3 separate
  subdivide<<<dim3((D2+255)/256, NV3), 256, 0, stream>>>(
      vf2, D2, NV2, ue2a, ue2b, verts3, 3, out + 1280, DOUT);
  pool_kernel<<<NV3, 256, 0, stream>>>(verts3, 3, NV3, f3, f4, f5, out, DOUT);
}

// Round 4
// 665.557 us; speedup vs baseline: 1.5260x; 1.5260x over previous
//
#include <hip/hip_runtime.h>
#include <hip/hip_bf16.h>
#include <stdint.h>

// ---- fixed problem geometry (GRID_N=41, deterministic) ----
#define NV1 1681
#define NF1 3200
#define NS1 (3*NF1)      // 9600 edge slots
#define NV2 6561
#define NF2 12800
#define NS2 (3*NF2)      // 38400 edge slots
#define NV3 25921
#define D1  1286         // valid cols: [verts(3) | perc1(1280) | verts(3)]
#define P1  1288         // padded row stride (16B aligned)
#define D2  2566         // valid cols: [verts2(3) | perc2(1280) | s2(1283)]
#define P2  2568         // padded row stride (16B aligned)
#define DOUT 3843        // [perc3(1280) | s3(2563)]
#define TSIZE 131072
#define TMASK (TSIZE-1)

// ---------------- feature transpose: in[R][Cc] -> out[Cc][R] ----------------
__global__ __launch_bounds__(256) void transpose32(
    const float* __restrict__ in, float* __restrict__ outp, int R, int Cc)
{
  __shared__ float tile[32][33];
  int bx = blockIdx.x * 32;   // col base (in)
  int by = blockIdx.y * 32;   // row base (in)
  int tx = threadIdx.x, ty = threadIdx.y;   // 32 x 8
  for (int j = ty; j < 32; j += 8) {
    int r = by + j, c = bx + tx;
    if (r < R && c < Cc) tile[j][tx] = in[(size_t)r*Cc + c];
  }
  __syncthreads();
  for (int j = ty; j < 32; j += 8) {
    int orow = bx + j, oc = by + tx;
    if (orow < Cc && oc < R) outp[(size_t)orow*R + oc] = tile[tx][j];
  }
}

// ---------------- pooling (channel-last features) ----------------
// one block (320 threads) per vertex; lane handles 4 consecutive channels.
// wave boundaries (c4 = 256, 768) are wave-uniform.
__global__ __launch_bounds__(320) void pool_t(
    const float* __restrict__ verts, int vstride, int nverts,
    const float* __restrict__ t3, const float* __restrict__ t4,
    const float* __restrict__ t5, float* __restrict__ out, int ostride)
{
  int v = blockIdx.x;
  if (v >= nverts) return;
  float X = verts[(size_t)v*vstride + 0];
  float Y = verts[(size_t)v*vstride + 1];
  float Z = verts[(size_t)v*vstride + 2];
  float p2 = Z + 0.8f;
  float px = (248.0f*X + 111.5f*Z + 89.2f) / p2;
  float py = (248.0f*Y + 111.5f*Z + 89.2f) / p2;

  int c4 = (int)threadIdx.x * 4;
  int m  = (c4 < 256) ? 0 : (c4 < 768) ? 1 : 2;
  int dim = (m == 0) ? 56 : (m == 1) ? 28 : 14;
  int C   = (m == 0) ? 256 : 512;
  int cb  = (m == 0) ? 0 : (m == 1) ? 256 : 768;
  const float* t = (m == 0) ? t3 : (m == 1) ? t4 : t5;

  float dimf = (float)dim;
  float x = fminf(fmaxf(px * dimf / 224.0f, 0.0f), dimf - 1.0f);
  float y = fminf(fmaxf(py * dimf / 224.0f, 0.0f), dimf - 1.0f);
  float x1 = floorf(x), x2 = ceilf(x);
  float y1 = floorf(y), y2 = ceilf(y);
  int xi1 = min(max((int)x1, 0), dim-1);
  int xi2 = min(max((int)x2, 0), dim-1);
  int yi1 = min(max((int)y1, 0), dim-1);
  int yi2 = min(max((int)y2, 0), dim-1);
  float w11 = (x2-x)*(y2-y), w12 = (x2-x)*(y-y1);
  float w21 = (x-x1)*(y2-y), w22 = (x-x1)*(y-y1);

  int cc = c4 - cb;
  const float4 f11 = *(const float4*)(t + (size_t)(xi1*dim + yi1)*C + cc);
  const float4 f12 = *(const float4*)(t + (size_t)(xi1*dim + yi2)*C + cc);
  const float4 f21 = *(const float4*)(t + (size_t)(xi2*dim + yi1)*C + cc);
  const float4 f22 = *(const float4*)(t + (size_t)(xi2*dim + yi2)*C + cc);

  float* o = out + (size_t)v*ostride + c4;
  o[0] = w11*f11.x + w12*f12.x + w21*f21.x + w22*f22.x;
  o[1] = w11*f11.y + w12*f12.y + w21*f21.y + w22*f22.y;
  o[2] = w11*f11.z + w12*f12.z + w21*f21.z + w22*f22.z;
  o[3] = w11*f11.w + w12*f12.w + w21*f21.w + w22*f22.w;
}

// write verts into vf1 cols 0:3 and 1283:1286
__global__ void copyverts1(const float* __restrict__ verts, float* __restrict__ vf1)
{
  int i = blockIdx.x*blockDim.x + threadIdx.x;
  if (i >= NV1*3) return;
  int r = i/3, c = i - 3*r;
  float v = verts[i];
  vf1[(size_t)r*P1 + c] = v;
  vf1[(size_t)r*P1 + 1283 + c] = v;
}

// ---------------- connectivity (replicates np.unique first-occurrence ranks) ----
__global__ void edge_insert(const int* __restrict__ faces, int F, int V,
                            unsigned* __restrict__ tkey, int* __restrict__ tmin,
                            unsigned* __restrict__ keys)
{
  int s = blockIdx.x*blockDim.x + threadIdx.x;
  if (s >= 3*F) return;
  int f = s/3, k = s - 3*f;
  int a0 = faces[3*f + k];
  int a1 = faces[3*f + (k == 2 ? 0 : k+1)];
  int a = min(a0, a1), b = max(a0, a1);
  unsigned key = (unsigned)a * (unsigned)V + (unsigned)b;
  keys[s] = key;
  unsigned h = (key * 2654435761u) & TMASK;
  while (true) {
    unsigned old = atomicCAS(&tkey[h], 0xFFFFFFFFu, key);
    if (old == 0xFFFFFFFFu || old == key) { atomicMin(&tmin[h], s); break; }
    h = (h+1) & TMASK;
  }
}

__global__ void edge_first(const unsigned* __restrict__ keys, int S,
                           const unsigned* __restrict__ tkey, const int* __restrict__ tmin,
                           int* __restrict__ fslot)
{
  int s = blockIdx.x*blockDim.x + threadIdx.x;
  if (s >= S) return;
  unsigned key = keys[s];
  unsigned h = (key * 2654435761u) & TMASK;
  while (tkey[h] != key) h = (h+1) & TMASK;
  fslot[s] = tmin[h];
}

// exclusive prefix sum of (fslot[i]==i): per-thread sequential + one ladder scan
__global__ __launch_bounds__(1024) void scan_excl(const int* __restrict__ fslot,
                                                  int* __restrict__ ranks, int n)
{
  __shared__ int tmp[1024];
  int tid = (int)threadIdx.x;
  int npt = (n + 1023) >> 10;
  int base = tid * npt;
  int cnt = 0;
  for (int j = 0; j < npt; ++j) {
    int i = base + j;
    if (i < n && fslot[i] == i) cnt++;
  }
  tmp[tid] = cnt;
  __syncthreads();
  for (int off = 1; off < 1024; off <<= 1) {
    int t = (tid >= off) ? tmp[tid - off] : 0;
    __syncthreads();
    tmp[tid] += t;
    __syncthreads();
  }
  int run = tmp[tid] - cnt;   // exclusive offset
  for (int j = 0; j < npt; ++j) {
    int i = base + j;
    if (i < n) { ranks[i] = run; if (fslot[i] == i) run++; }
  }
}

__global__ void edge_mid(const unsigned* __restrict__ keys, const int* __restrict__ fslot,
                         const int* __restrict__ ranks, int S, int V,
                         int* __restrict__ mid, int* __restrict__ uea, int* __restrict__ ueb)
{
  int s = blockIdx.x*blockDim.x + threadIdx.x;
  if (s >= S) return;
  int fs = fslot[s];
  int r = ranks[fs];
  mid[s] = V + r;
  if (fs == s) {
    unsigned key = keys[s];
    uea[r] = (int)(key / (unsigned)V);
    ueb[r] = (int)(key % (unsigned)V);
  }
}

__global__ void new_faces(const int* __restrict__ faces, int F,
                          const int* __restrict__ mid, int* __restrict__ nf)
{
  int f = blockIdx.x*blockDim.x + threadIdx.x;
  if (f >= F) return;
  int i1 = faces[3*f], i2 = faces[3*f+1], i3 = faces[3*f+2];
  int i4 = mid[3*f], i5 = mid[3*f+1], i6 = mid[3*f+2];
  int* o = nf + 12*f;
  o[0]=i1; o[1]=i4; o[2]=i6;
  o[3]=i2; o[4]=i4; o[5]=i5;
  o[6]=i3; o[7]=i5; o[8]=i6;
  o[9]=i5; o[10]=i4; o[11]=i6;
}

// ---------------- subdivision feature propagation (float4 reads) ----------------
// row r < Vold: copy src row; else midpoint of rows uea/ueb.
// col<3 -> dstV (stride dvs), else dstS (pre-offset base, stride dss).
__global__ __launch_bounds__(256) void subdivide4(
    const float* __restrict__ src, int P, int D, int Vold,
    const int* __restrict__ uea, const int* __restrict__ ueb,
    float* __restrict__ dstV, int dvs, float* __restrict__ dstS, int dss)
{
  int c4 = (blockIdx.x*256 + (int)threadIdx.x) * 4;
  int r = blockIdx.y;
  if (c4 >= D) return;
  float4 val;
  if (r < Vold) {
    val = *(const float4*)(src + (size_t)r*P + c4);
  } else {
    int e = r - Vold;
    int a = uea[e], b = ueb[e];
    float4 va = *(const float4*)(src + (size_t)a*P + c4);
    float4 vb = *(const float4*)(src + (size_t)b*P + c4);
    val.x = 0.5f*(va.x+vb.x); val.y = 0.5f*(va.y+vb.y);
    val.z = 0.5f*(va.z+vb.z); val.w = 0.5f*(va.w+vb.w);
  }
  float vv[4] = {val.x, val.y, val.z, val.w};
#pragma unroll
  for (int t = 0; t < 4; ++t) {
    int c = c4 + t;
    if (c < D) {
      if (c < 3) dstV[(size_t)r*dvs + c] = vv[t];
      else       dstS[(size_t)r*dss + (c-3)] = vv[t];
    }
  }
}

// ---------------- host ----------------
static inline char* bump(char*& p, size_t bytes) {
  char* r = p;
  p += (bytes + 255) & ~(size_t)255;
  return r;
}

extern "C" void kernel_launch(void* const* d_in, const int* in_sizes, int n_in,
                              void* d_out, int out_size, void* d_ws, size_t ws_size,
                              hipStream_t stream)
{
  const float* f3    = (const float*)d_in[0];
  const float* f4    = (const float*)d_in[1];
  const float* f5    = (const float*)d_in[2];
  const float* verts = (const float*)d_in[3];
  const int*   faces = (const int*)d_in[4];
  float* out = (float*)d_out;

  char* p = (char*)d_ws;
  float* t3     = (float*)bump(p, (size_t)3136*256*4);
  float* t4     = (float*)bump(p, (size_t)784*512*4);
  float* t5     = (float*)bump(p, (size_t)196*512*4);
  float* vf1    = (float*)bump(p, (size_t)NV1*P1*4);
  float* vf2    = (float*)bump(p, (size_t)NV2*P2*4);
  float* verts3 = (float*)bump(p, (size_t)NV3*3*4);
  int*   faces2 = (int*)  bump(p, (size_t)NF2*3*4);
  unsigned* key1 = (unsigned*)bump(p, (size_t)NS1*4);
  int* fslot1 = (int*)bump(p, (size_t)NS1*4);
  int* rank1  = (int*)bump(p, (size_t)NS1*4);
  int* mid1   = (int*)bump(p, (size_t)NS1*4);
  int* ue1a   = (int*)bump(p, (size_t)NS1*4);
  int* ue1b   = (int*)bump(p, (size_t)NS1*4);
  unsigned* key2 = (unsigned*)bump(p, (size_t)NS2*4);
  int* fslot2 = (int*)bump(p, (size_t)NS2*4);
  int* rank2  = (int*)bump(p, (size_t)NS2*4);
  int* mid2   = (int*)bump(p, (size_t)NS2*4);
  int* ue2a   = (int*)bump(p, (size_t)NS2*4);
  int* ue2b   = (int*)bump(p, (size_t)NS2*4);
  unsigned* tkey1 = (unsigned*)bump(p, (size_t)TSIZE*4);
  int*      tmin1 = (int*)     bump(p, (size_t)TSIZE*4);
  unsigned* tkey2 = (unsigned*)bump(p, (size_t)TSIZE*4);
  int*      tmin2 = (int*)     bump(p, (size_t)TSIZE*4);

  // hash table init: keys = 0xFFFFFFFF (empty), mins = 0x7F7F7F7F (+inf)
  hipMemsetAsync(tkey1, 0xFF, (size_t)TSIZE*4, stream);
  hipMemsetAsync(tmin1, 0x7F, (size_t)TSIZE*4, stream);
  hipMemsetAsync(tkey2, 0xFF, (size_t)TSIZE*4, stream);
  hipMemsetAsync(tmin2, 0x7F, (size_t)TSIZE*4, stream);

  // ---- feature transpose to channel-last: t[pos][c] ----
  transpose32<<<dim3((3136+31)/32, (256+31)/32), dim3(32,8), 0, stream>>>(f3, t3, 256, 3136);
  transpose32<<<dim3(( 784+31)/32, (512+31)/32), dim3(32,8), 0, stream>>>(f4, t4, 512,  784);
  transpose32<<<dim3(( 196+31)/32, (512+31)/32), dim3(32,8), 0, stream>>>(f5, t5, 512,  196);

  // ---- level 1 ----
  copyverts1<<<(NV1*3 + 255)/256, 256, 0, stream>>>(verts, vf1);
  pool_t<<<NV1, 320, 0, stream>>>(verts, 3, NV1, t3, t4, t5, vf1 + 3, P1);

  edge_insert<<<(NS1+255)/256, 256, 0, stream>>>(faces, NF1, NV1, tkey1, tmin1, key1);
  edge_first <<<(NS1+255)/256, 256, 0, stream>>>(key1, NS1, tkey1, tmin1, fslot1);
  scan_excl  <<<1, 1024, 0, stream>>>(fslot1, rank1, NS1);
  edge_mid   <<<(NS1+255)/256, 256, 0, stream>>>(key1, fslot1, rank1, NS1, NV1, mid1, ue1a, ue1b);
  new_faces  <<<(NF1+255)/256, 256, 0, stream>>>(faces, NF1, mid1, faces2);

  // vf2 = [verts2(0:3) | perc2(3:1283) | s2(1283:2566)], padded stride P2
  subdivide4<<<dim3(2, NV2), 256, 0, stream>>>(
      vf1, P1, D1, NV1, ue1a, ue1b, vf2, P2, vf2 + 1283, P2);
  pool_t<<<NV2, 320, 0, stream>>>(vf2, P2, NV2, t3, t4, t5, vf2 + 3, P2);

  // ---- level 2 ----
  edge_insert<<<(NS2+255)/256, 256, 0, stream>>>(faces2, NF2, NV2, tkey2, tmin2, key2);
  edge_first <<<(NS2+255)/256, 256, 0, stream>>>(key2, NS2, tkey2, tmin2, fslot2);
  scan_excl  <<<1, 1024, 0, stream>>>(fslot2, rank2, NS2);
  edge_mid   <<<(NS2+255)/256, 256, 0, stream>>>(key2, fslot2, rank2, NS2, NV2, mid2, ue2a, ue2b);

  // out = [perc3(0:1280) | s3(1280:3843)], verts3 separate
  subdivide4<<<dim3(3, NV3), 256, 0, stream>>>(
      vf2, P2, D2, NV2, ue2a, ue2b, verts3, 3, out + 1280, DOUT);
  pool_t<<<NV3, 320, 0, stream>>>(verts3, 3, NV3, t3, t4, t5, out, DOUT);
}